// Round 1
// 196.096 us; speedup vs baseline: 1.0801x; 1.0801x over previous
//
#include <hip/hip_runtime.h>
#include <hip/hip_bf16.h>

// Problem constants (B,T,C,H,DH) = (2,2048,768,12,64)
#define Bn 2
#define Tn 2048
#define Cn 768
#define Hn 12
#define Dn 64
#define N3n 2304
#define Mn 4096   // B*T

#define MASKVAL (-30000.f)   // finite sentinel; scores are O(+-15)
#define NITEMS 768           // 32 q-tiles * 12 heads * 2 batch

typedef unsigned short u16;
typedef __attribute__((ext_vector_type(8))) unsigned short ushort8_t;
typedef __attribute__((ext_vector_type(8))) short bf16x8;   // 8 bf16 in 4 VGPRs
typedef __attribute__((ext_vector_type(4))) float f32x4;

__device__ __forceinline__ float bf2f(u16 u) {
  union { unsigned int i; float f; } v; v.i = ((unsigned int)u) << 16; return v.f;
}
__device__ __forceinline__ u16 f2bf(float f) {
  union { float f; unsigned int i; } v; v.f = f;
  return (u16)((v.i + 0x7fffu + ((v.i >> 16) & 1u)) >> 16);
}
__device__ __forceinline__ float safe_exp(float x) {
  return __expf(fmaxf(x, -80.f));   // arg in [-80,0]; never inf/NaN
}

// ---------------------------------------------------------------------------
// Prep 1: elementwise fp32 -> bf16 cast (x). Also zeroes the attn work counter
// (block 0, thread 0) — runs before attn in stream order, so no extra dispatch.
// ---------------------------------------------------------------------------
__global__ __launch_bounds__(256) void cast_bf16(const float* __restrict__ in,
                                                 u16* __restrict__ out,
                                                 int* __restrict__ counter) {
  if (blockIdx.x == 0 && threadIdx.x == 0) *counter = 0;
  const int i = (blockIdx.x * 256 + threadIdx.x) * 4;
  float4 v = *(const float4*)(in + i);
  ushort4 s;
  s.x = f2bf(v.x); s.y = f2bf(v.y); s.z = f2bf(v.z); s.w = f2bf(v.w);
  *(ushort4*)(out + i) = s;
}

// ---------------------------------------------------------------------------
// Prep 2: transpose-cast. in fp32 [R][Cc] -> out bf16 [Cc][R]. 32x32 LDS tile.
// ---------------------------------------------------------------------------
__global__ __launch_bounds__(256) void transpose_cast(const float* __restrict__ in,
                                                      u16* __restrict__ out,
                                                      int R, int Cc) {
  __shared__ u16 t[32][33];
  const int c0 = blockIdx.x * 32, r0 = blockIdx.y * 32;
  const int tx = threadIdx.x, ty = threadIdx.y;
#pragma unroll
  for (int i = 0; i < 4; i++)
    t[ty * 4 + i][tx] = f2bf(in[(size_t)(r0 + ty * 4 + i) * Cc + c0 + tx]);
  __syncthreads();
#pragma unroll
  for (int i = 0; i < 4; i++)
    out[(size_t)(c0 + ty * 4 + i) * R + r0 + tx] = t[tx][ty * 4 + i];
}

// ---------------------------------------------------------------------------
// MFMA GEMM (unchanged — verified). 128x128 tile, BK=32, 4 waves.
// ---------------------------------------------------------------------------
#define GP 40

template <int EPI>
__global__ __launch_bounds__(256) void mfma_gemm(const u16* __restrict__ A,
                                                 const u16* __restrict__ BT,
                                                 u16* __restrict__ Q,
                                                 u16* __restrict__ Kd,
                                                 u16* __restrict__ VT,
                                                 float* __restrict__ out) {
  __shared__ __align__(16) u16 Ash[128 * GP];
  __shared__ __align__(16) u16 Bsh[128 * GP];
  const int tid = threadIdx.x;
  const int wv = tid >> 6, lane = tid & 63;
  const int lo = lane & 15, quad = lane >> 4;
  const int wm = wv & 1, wn = wv >> 1;
  const int n0 = blockIdx.x * 128;
  const int m0 = blockIdx.y * 128;

  f32x4 acc[4][4];
#pragma unroll
  for (int i = 0; i < 4; i++)
#pragma unroll
    for (int j = 0; j < 4; j++) acc[i][j] = f32x4{0.f, 0.f, 0.f, 0.f};

  for (int k0 = 0; k0 < Cn; k0 += 32) {
    __syncthreads();
#pragma unroll
    for (int it = 0; it < 2; it++) {
      const int c = tid + it * 256;
      const int row = c >> 2, col = (c & 3) << 3;
      *(ushort8_t*)&Ash[row * GP + col] =
          *(const ushort8_t*)(A + (size_t)(m0 + row) * Cn + k0 + col);
      *(ushort8_t*)&Bsh[row * GP + col] =
          *(const ushort8_t*)(BT + (size_t)(n0 + row) * Cn + k0 + col);
    }
    __syncthreads();

    bf16x8 af[4], bfr[4];
#pragma unroll
    for (int t = 0; t < 4; t++) {
      af[t]  = *(const bf16x8*)&Ash[(wm * 64 + t * 16 + lo) * GP + (quad << 3)];
      bfr[t] = *(const bf16x8*)&Bsh[(wn * 64 + t * 16 + lo) * GP + (quad << 3)];
    }
#pragma unroll
    for (int mt = 0; mt < 4; mt++)
#pragma unroll
      for (int nt = 0; nt < 4; nt++)
        acc[mt][nt] = __builtin_amdgcn_mfma_f32_16x16x32_bf16(af[mt], bfr[nt],
                                                              acc[mt][nt], 0, 0, 0);
  }

  if (EPI == 0) {
    const int which = n0 / Cn;
    const int h = ((n0 % Cn) >> 6) + wn;
    const int bb = m0 >> 11;
    const int t_base = (m0 & (Tn - 1)) + wm * 64;
    if (which < 2) {
      u16* dst = ((which == 0) ? Q : Kd) + (size_t)(bb * Hn + h) * Tn * Dn;
#pragma unroll
      for (int mt = 0; mt < 4; mt++)
#pragma unroll
        for (int nt = 0; nt < 4; nt++)
#pragma unroll
          for (int r = 0; r < 4; r++) {
            const int t = t_base + mt * 16 + (quad << 2) + r;
            dst[(size_t)t * Dn + nt * 16 + lo] = f2bf(acc[mt][nt][r]);
          }
    } else {
      u16* dst = VT + (size_t)(bb * Hn + h) * Dn * Tn;
#pragma unroll
      for (int mt = 0; mt < 4; mt++)
#pragma unroll
        for (int nt = 0; nt < 4; nt++) {
          const int t = t_base + mt * 16 + (quad << 2);
          const int d = nt * 16 + lo;
          ushort4 st;
          st.x = f2bf(acc[mt][nt][0]); st.y = f2bf(acc[mt][nt][1]);
          st.z = f2bf(acc[mt][nt][2]); st.w = f2bf(acc[mt][nt][3]);
          *(ushort4*)&dst[(size_t)d * Tn + t] = st;
        }
    }
  } else {
#pragma unroll
    for (int mt = 0; mt < 4; mt++)
#pragma unroll
      for (int nt = 0; nt < 4; nt++)
#pragma unroll
        for (int r = 0; r < 4; r++) {
          const int m = m0 + wm * 64 + mt * 16 + (quad << 2) + r;
          out[(size_t)m * Cn + n0 + wn * 64 + nt * 16 + lo] = acc[mt][nt][r];
        }
  }
}

// ---------------------------------------------------------------------------
// Causal flash attention, restructured (R6):
//  * swapped QK^T:  S^T = mfma(K_frag, Q_frag)  -> each lane owns ONE q-row's
//    16 scores (q = lo, kv = nt*16 + quad*4 + r).  Softmax = local tree +
//    2 shfl_xor (vs 32 shfls before); m/l are per-lane scalars.
//  * P round-trip: 4x ds_write_b64 (kv-contiguous) instead of 16x ds_write_b16.
//  * per-row alpha / 1/l transposed back with 4 __shfl's (row q=quad*4+r lives
//    in lane lo=quad*4+r).
//  * double-buffered K/V LDS + register prefetch: ONE __syncthreads per
//    kv-tile; next tile's global loads issued before compute (latency hidden).
//  * grid 512 -> 768 blocks (one LPT item each; 46 KB LDS -> 3 blocks/CU).
// ---------------------------------------------------------------------------
#define KP 72              // LDS row pitch in u16 (144 B: 16B-aligned)
#define TILE_W (64 * KP)   // one K or V tile in u16

__global__ __launch_bounds__(256) void attn_kernel(const u16* __restrict__ Q,
                                                   const u16* __restrict__ K,
                                                   const u16* __restrict__ VT,
                                                   u16* __restrict__ O,
                                                   int* __restrict__ counter) {
  __shared__ __align__(16) u16 Ksh[2 * TILE_W];   // K tiles  [kv_row][d], x2
  __shared__ __align__(16) u16 Vsh[2 * TILE_W];   // V tiles  [d][kv_row], x2
  __shared__ __align__(16) u16 Pw[4][16 * KP];    // per-wave P [q_row][kv]
  __shared__ int s_item;

  const int tid = threadIdx.x;
  const int wv = tid >> 6, lane = tid & 63;
  const int lo = lane & 15, quad = lane >> 4;
  const int sr = tid >> 3;            // staging row 0..31
  const int sc = (tid & 7) << 3;      // staging col (u16) 0..56

  for (;;) {
    if (tid == 0) s_item = atomicAdd(counter, 1);
    __syncthreads();                  // broadcast item; fences LDS reuse
    const int item = s_item;
    if (item >= NITEMS) return;       // uniform exit

    // LPT decode: longest q-tiles first
    const int q0 = (31 - item / 24) * 64;
    const int hb = item % 24;
    const int h = hb % 12, b = hb / 12;
    const size_t base = (size_t)(b * Hn + h) * Tn * Dn;   // Q/K [.,T,64]
    const size_t vtb  = (size_t)(b * Hn + h) * Dn * Tn;   // VT  [.,64,T]

    const u16* qp = Q + base + (size_t)(q0 + (wv << 4) + lo) * Dn + (quad << 3);
    const bf16x8 aq0 = *(const bf16x8*)qp;
    const bf16x8 aq1 = *(const bf16x8*)(qp + 32);

    f32x4 o[4] = {f32x4{0,0,0,0}, f32x4{0,0,0,0}, f32x4{0,0,0,0}, f32x4{0,0,0,0}};
    float m1 = MASKVAL;               // running max for q-row (wv*16 + lo)
    float l1 = 0.f;                   // running denom for same row

    // prologue: stage kv-tile 0 into buffer 0
#pragma unroll
    for (int it = 0; it < 2; it++) {
      const int r = sr + it * 32;
      *(ushort8_t*)&Ksh[r * KP + sc] =
          *(const ushort8_t*)(K + base + (size_t)r * Dn + sc);
      *(ushort8_t*)&Vsh[r * KP + sc] =
          *(const ushort8_t*)(VT + vtb + (size_t)r * Tn + sc);
    }
    __syncthreads();

    int cur = 0;
    const int qrel = (wv << 4) + lo;  // this lane's q-row within the 64-q tile

    for (int j0 = 0; j0 <= q0; j0 += 64) {
      const bool hasnext = (j0 + 64 <= q0);

      // T14: issue next tile's global loads NOW; write to LDS after compute
      ushort8_t kr[2], vr[2];
      if (hasnext) {
#pragma unroll
        for (int it = 0; it < 2; it++) {
          const int r = sr + it * 32;
          kr[it] = *(const ushort8_t*)(K + base + (size_t)(j0 + 64 + r) * Dn + sc);
          vr[it] = *(const ushort8_t*)(VT + vtb + (size_t)r * Tn + j0 + 64 + sc);
        }
      }

      const u16* Kb_ = &Ksh[cur * TILE_W];
      const u16* Vb_ = &Vsh[cur * TILE_W];

      // QK^T swapped: A = K-tile rows (m = kv), B = Q rows (n = q)
      f32x4 s[4];
#pragma unroll
      for (int nt = 0; nt < 4; nt++) {
        const bf16x8 bk0 = *(const bf16x8*)(&Kb_[(nt * 16 + lo) * KP + (quad << 3)]);
        const bf16x8 bk1 = *(const bf16x8*)(&Kb_[(nt * 16 + lo) * KP + 32 + (quad << 3)]);
        f32x4 a = {0.f, 0.f, 0.f, 0.f};
        a = __builtin_amdgcn_mfma_f32_16x16x32_bf16(bk0, aq0, a, 0, 0, 0);
        a = __builtin_amdgcn_mfma_f32_16x16x32_bf16(bk1, aq1, a, 0, 0, 0);
        s[nt] = a;   // s[nt][r] = S[q = qrel][kv = nt*16 + quad*4 + r]
      }

      if (j0 == q0) {
#pragma unroll
        for (int nt = 0; nt < 4; nt++)
#pragma unroll
          for (int r = 0; r < 4; r++) {
            const int kv = nt * 16 + (quad << 2) + r;
            s[nt][r] = (kv > qrel) ? MASKVAL : s[nt][r] * 0.125f;
          }
      } else {
#pragma unroll
        for (int nt = 0; nt < 4; nt++)
#pragma unroll
          for (int r = 0; r < 4; r++) s[nt][r] *= 0.125f;
      }

      // online softmax for this lane's q-row: local tree + 2-step quad reduce
      const float mxa = fmaxf(fmaxf(s[0][0], s[0][1]), fmaxf(s[0][2], s[0][3]));
      const float mxb = fmaxf(fmaxf(s[1][0], s[1][1]), fmaxf(s[1][2], s[1][3]));
      const float mxc = fmaxf(fmaxf(s[2][0], s[2][1]), fmaxf(s[2][2], s[2][3]));
      const float mxd = fmaxf(fmaxf(s[3][0], s[3][1]), fmaxf(s[3][2], s[3][3]));
      float mx = fmaxf(fmaxf(mxa, mxb), fmaxf(mxc, mxd));
      mx = fmaxf(mx, __shfl_xor(mx, 16));
      mx = fmaxf(mx, __shfl_xor(mx, 32));
      const float mnew = fmaxf(m1, mx);
      const float alpha = safe_exp(m1 - mnew);
      m1 = mnew;

      float sum = 0.f;
#pragma unroll
      for (int nt = 0; nt < 4; nt++)
#pragma unroll
        for (int r = 0; r < 4; r++) {
          const float p = safe_exp(s[nt][r] - mnew);
          s[nt][r] = p;
          sum += p;
        }
      sum += __shfl_xor(sum, 16);
      sum += __shfl_xor(sum, 32);
      l1 = l1 * alpha + sum;

      // P -> LDS bf16: r is kv-contiguous -> one ds_write_b64 per nt
      u16* pw = Pw[wv];
#pragma unroll
      for (int nt = 0; nt < 4; nt++) {
        ushort4 pk;
        pk.x = f2bf(s[nt][0]); pk.y = f2bf(s[nt][1]);
        pk.z = f2bf(s[nt][2]); pk.w = f2bf(s[nt][3]);
        *(ushort4*)&pw[lo * KP + nt * 16 + (quad << 2)] = pk;
      }
      const bf16x8 pa0 = *(const bf16x8*)(&pw[lo * KP + (quad << 3)]);
      const bf16x8 pa1 = *(const bf16x8*)(&pw[lo * KP + 32 + (quad << 3)]);

      // per-output-row alpha: row q=quad*4+r is owned by lane lo=quad*4+r
      float ar[4];
#pragma unroll
      for (int r = 0; r < 4; r++) ar[r] = __shfl(alpha, (quad << 2) + r);

#pragma unroll
      for (int nt = 0; nt < 4; nt++) {
#pragma unroll
        for (int r = 0; r < 4; r++) o[nt][r] *= ar[r];
        const bf16x8 bv0 = *(const bf16x8*)(&Vb_[(nt * 16 + lo) * KP + (quad << 3)]);
        const bf16x8 bv1 = *(const bf16x8*)(&Vb_[(nt * 16 + lo) * KP + 32 + (quad << 3)]);
        o[nt] = __builtin_amdgcn_mfma_f32_16x16x32_bf16(pa0, bv0, o[nt], 0, 0, 0);
        o[nt] = __builtin_amdgcn_mfma_f32_16x16x32_bf16(pa1, bv1, o[nt], 0, 0, 0);
      }

      // write prefetched next tile into the other buffer, then single barrier
      if (hasnext) {
        const int nb = cur ^ 1;
#pragma unroll
        for (int it = 0; it < 2; it++) {
          const int r = sr + it * 32;
          *(ushort8_t*)&Ksh[nb * TILE_W + r * KP + sc] = kr[it];
          *(ushort8_t*)&Vsh[nb * TILE_W + r * KP + sc] = vr[it];
        }
      }
      __syncthreads();
      cur ^= 1;
    }

    // epilogue: 1/l for row q=quad*4+r lives in lane lo=quad*4+r
    const float linv = 1.f / l1;
    float ir[4];
#pragma unroll
    for (int r = 0; r < 4; r++) ir[r] = __shfl(linv, (quad << 2) + r);
#pragma unroll
    for (int nt = 0; nt < 4; nt++)
#pragma unroll
      for (int r = 0; r < 4; r++) {
        const int row = q0 + (wv << 4) + (quad << 2) + r;
        const int col = h * 64 + nt * 16 + lo;
        O[(size_t)(b * Tn + row) * Cn + col] = f2bf(o[nt][r] * ir[r]);
      }
  }
}

// ---------------------------------------------------------------------------
extern "C" void kernel_launch(void* const* d_in, const int* in_sizes, int n_in,
                              void* d_out, int out_size, void* d_ws, size_t ws_size,
                              hipStream_t stream) {
  const float* x    = (const float*)d_in[0];   // [B,T,C] fp32
  const float* Wqkv = (const float*)d_in[1];   // [C,3C] fp32
  const float* Wout = (const float*)d_in[2];   // [C,C] fp32
  float* out = (float*)d_out;                  // [B,T,C] fp32

  const size_t per = (size_t)Bn * Hn * Tn * Dn;     // 3,145,728 elems
  u16* xb    = (u16*)d_ws;                          // [4096,768] bf16
  u16* WqkvT = xb + (size_t)Mn * Cn;                // [2304,768] bf16
  u16* WoutT = WqkvT + (size_t)N3n * Cn;            // [768,768]  bf16
  u16* Qb    = WoutT + (size_t)Cn * Cn;             // [B,H,T,DH] bf16
  u16* Kb    = Qb + per;                            // [B,H,T,DH] bf16
  u16* VTb   = Kb + per;                            // [B,H,DH,T] bf16
  u16* attn  = VTb + per;                           // [B,T,C]    bf16
  int* counter = (int*)(attn + (size_t)Mn * Cn);    // 4 B, 4-aligned
  // total ws use: ~36.2 MB + 4 B (< 50.3 MB available)

  cast_bf16<<<(Mn * Cn) / 1024, 256, 0, stream>>>(x, xb, counter);
  transpose_cast<<<dim3(N3n / 32, Cn / 32), dim3(32, 8), 0, stream>>>(Wqkv, WqkvT, Cn, N3n);
  transpose_cast<<<dim3(Cn / 32, Cn / 32), dim3(32, 8), 0, stream>>>(Wout, WoutT, Cn, Cn);

  mfma_gemm<0><<<dim3(N3n / 128, Mn / 128), 256, 0, stream>>>(xb, WqkvT, Qb, Kb, VTb, nullptr);
  attn_kernel<<<dim3(768), 256, 0, stream>>>(Qb, Kb, VTb, attn, counter);
  mfma_gemm<1><<<dim3(Cn / 128, Mn / 128), 256, 0, stream>>>(attn, WoutT, nullptr, nullptr, nullptr, out);
}

// Round 2
// 186.015 us; speedup vs baseline: 1.1386x; 1.0542x over previous
//
#include <hip/hip_runtime.h>
#include <hip/hip_bf16.h>

// Problem constants (B,T,C,H,DH) = (2,2048,768,12,64)
#define Bn 2
#define Tn 2048
#define Cn 768
#define Hn 12
#define Dn 64
#define N3n 2304
#define Mn 4096   // B*T

#define MASKVAL (-30000.f)   // finite sentinel; scores are O(+-15) unscaled
#define NITEMS 768           // 32 q-tiles * 12 heads * 2 batch
#define DEFER_THR 64.f       // unscaled-score gap; P bounded by e^(64*0.125)=e^8

typedef unsigned short u16;
typedef __attribute__((ext_vector_type(8))) unsigned short ushort8_t;
typedef __attribute__((ext_vector_type(8))) short bf16x8;   // 8 bf16 in 4 VGPRs
typedef __attribute__((ext_vector_type(4))) float f32x4;

__device__ __forceinline__ float bf2f(u16 u) {
  union { unsigned int i; float f; } v; v.i = ((unsigned int)u) << 16; return v.f;
}
__device__ __forceinline__ u16 f2bf(float f) {
  union { float f; unsigned int i; } v; v.f = f;
  return (u16)((v.i + 0x7fffu + ((v.i >> 16) & 1u)) >> 16);
}
__device__ __forceinline__ float safe_exp(float x) {
  return __expf(fmaxf(x, -80.f));   // arg in [-80,+8]; never inf/NaN
}

// ---------------------------------------------------------------------------
// Prep 1: elementwise fp32 -> bf16 cast (x). Also zeroes the attn work counter
// (block 0, thread 0) — runs before attn in stream order, so no extra dispatch.
// ---------------------------------------------------------------------------
__global__ __launch_bounds__(256) void cast_bf16(const float* __restrict__ in,
                                                 u16* __restrict__ out,
                                                 int* __restrict__ counter) {
  if (blockIdx.x == 0 && threadIdx.x == 0) *counter = 0;
  const int i = (blockIdx.x * 256 + threadIdx.x) * 4;
  float4 v = *(const float4*)(in + i);
  ushort4 s;
  s.x = f2bf(v.x); s.y = f2bf(v.y); s.z = f2bf(v.z); s.w = f2bf(v.w);
  *(ushort4*)(out + i) = s;
}

// ---------------------------------------------------------------------------
// Prep 2: transpose-cast. in fp32 [R][Cc] -> out bf16 [Cc][R]. 32x32 LDS tile.
// ---------------------------------------------------------------------------
__global__ __launch_bounds__(256) void transpose_cast(const float* __restrict__ in,
                                                      u16* __restrict__ out,
                                                      int R, int Cc) {
  __shared__ u16 t[32][33];
  const int c0 = blockIdx.x * 32, r0 = blockIdx.y * 32;
  const int tx = threadIdx.x, ty = threadIdx.y;
#pragma unroll
  for (int i = 0; i < 4; i++)
    t[ty * 4 + i][tx] = f2bf(in[(size_t)(r0 + ty * 4 + i) * Cc + c0 + tx]);
  __syncthreads();
#pragma unroll
  for (int i = 0; i < 4; i++)
    out[(size_t)(c0 + ty * 4 + i) * R + r0 + tx] = t[tx][ty * 4 + i];
}

// ---------------------------------------------------------------------------
// MFMA GEMM (unchanged — verified). 128x128 tile, BK=32, 4 waves.
// ---------------------------------------------------------------------------
#define GP 40

template <int EPI>
__global__ __launch_bounds__(256) void mfma_gemm(const u16* __restrict__ A,
                                                 const u16* __restrict__ BT,
                                                 u16* __restrict__ Q,
                                                 u16* __restrict__ Kd,
                                                 u16* __restrict__ VT,
                                                 float* __restrict__ out) {
  __shared__ __align__(16) u16 Ash[128 * GP];
  __shared__ __align__(16) u16 Bsh[128 * GP];
  const int tid = threadIdx.x;
  const int wv = tid >> 6, lane = tid & 63;
  const int lo = lane & 15, quad = lane >> 4;
  const int wm = wv & 1, wn = wv >> 1;
  const int n0 = blockIdx.x * 128;
  const int m0 = blockIdx.y * 128;

  f32x4 acc[4][4];
#pragma unroll
  for (int i = 0; i < 4; i++)
#pragma unroll
    for (int j = 0; j < 4; j++) acc[i][j] = f32x4{0.f, 0.f, 0.f, 0.f};

  for (int k0 = 0; k0 < Cn; k0 += 32) {
    __syncthreads();
#pragma unroll
    for (int it = 0; it < 2; it++) {
      const int c = tid + it * 256;
      const int row = c >> 2, col = (c & 3) << 3;
      *(ushort8_t*)&Ash[row * GP + col] =
          *(const ushort8_t*)(A + (size_t)(m0 + row) * Cn + k0 + col);
      *(ushort8_t*)&Bsh[row * GP + col] =
          *(const ushort8_t*)(BT + (size_t)(n0 + row) * Cn + k0 + col);
    }
    __syncthreads();

    bf16x8 af[4], bfr[4];
#pragma unroll
    for (int t = 0; t < 4; t++) {
      af[t]  = *(const bf16x8*)&Ash[(wm * 64 + t * 16 + lo) * GP + (quad << 3)];
      bfr[t] = *(const bf16x8*)&Bsh[(wn * 64 + t * 16 + lo) * GP + (quad << 3)];
    }
#pragma unroll
    for (int mt = 0; mt < 4; mt++)
#pragma unroll
      for (int nt = 0; nt < 4; nt++)
        acc[mt][nt] = __builtin_amdgcn_mfma_f32_16x16x32_bf16(af[mt], bfr[nt],
                                                              acc[mt][nt], 0, 0, 0);
  }

  if (EPI == 0) {
    const int which = n0 / Cn;
    const int h = ((n0 % Cn) >> 6) + wn;
    const int bb = m0 >> 11;
    const int t_base = (m0 & (Tn - 1)) + wm * 64;
    if (which < 2) {
      u16* dst = ((which == 0) ? Q : Kd) + (size_t)(bb * Hn + h) * Tn * Dn;
#pragma unroll
      for (int mt = 0; mt < 4; mt++)
#pragma unroll
        for (int nt = 0; nt < 4; nt++)
#pragma unroll
          for (int r = 0; r < 4; r++) {
            const int t = t_base + mt * 16 + (quad << 2) + r;
            dst[(size_t)t * Dn + nt * 16 + lo] = f2bf(acc[mt][nt][r]);
          }
    } else {
      u16* dst = VT + (size_t)(bb * Hn + h) * Dn * Tn;
#pragma unroll
      for (int mt = 0; mt < 4; mt++)
#pragma unroll
        for (int nt = 0; nt < 4; nt++) {
          const int t = t_base + mt * 16 + (quad << 2);
          const int d = nt * 16 + lo;
          ushort4 st;
          st.x = f2bf(acc[mt][nt][0]); st.y = f2bf(acc[mt][nt][1]);
          st.z = f2bf(acc[mt][nt][2]); st.w = f2bf(acc[mt][nt][3]);
          *(ushort4*)&dst[(size_t)d * Tn + t] = st;
        }
    }
  } else {
#pragma unroll
    for (int mt = 0; mt < 4; mt++)
#pragma unroll
      for (int nt = 0; nt < 4; nt++)
#pragma unroll
        for (int r = 0; r < 4; r++) {
          const int m = m0 + wm * 64 + mt * 16 + (quad << 2) + r;
          out[(size_t)m * Cn + n0 + wn * 64 + nt * 16 + lo] = acc[mt][nt][r];
        }
  }
}

// ---------------------------------------------------------------------------
// Causal flash attention (R7):
//  * grid back to 512 blocks + dynamic LPT stealing (768 items / 512 blocks
//    -> real load balancing; 768/768 in R6 degenerated to 1 item/block and
//    the longest item set the kernel duration).
//  * defer-max (T13): common path skips cross-quad max reduce, alpha, the
//    4 alpha-transpose shuffles and the o-rescale; triggered only when
//    __all(pmax <= m1 + 64) fails (rare after the first tile).
//  * per-lane partial l (each quad owns disjoint kv cols) -> NO per-step sum
//    shuffles; one cross-quad reduce per item in the epilogue.
//  * 0.125 scale folded into the exp argument (compares are monotone).
//  Common path: zero cross-lane ops per tile-step.
// ---------------------------------------------------------------------------
#define KP 72              // LDS row pitch in u16 (144 B: 16B-aligned)
#define TILE_W (64 * KP)   // one K or V tile in u16

__global__ __launch_bounds__(256) void attn_kernel(const u16* __restrict__ Q,
                                                   const u16* __restrict__ K,
                                                   const u16* __restrict__ VT,
                                                   u16* __restrict__ O,
                                                   int* __restrict__ counter) {
  __shared__ __align__(16) u16 Ksh[2 * TILE_W];   // K tiles  [kv_row][d], x2
  __shared__ __align__(16) u16 Vsh[2 * TILE_W];   // V tiles  [d][kv_row], x2
  __shared__ __align__(16) u16 Pw[4][16 * KP];    // per-wave P [q_row][kv]
  __shared__ int s_item;

  const int tid = threadIdx.x;
  const int wv = tid >> 6, lane = tid & 63;
  const int lo = lane & 15, quad = lane >> 4;
  const int sr = tid >> 3;            // staging row 0..31
  const int sc = (tid & 7) << 3;      // staging col (u16) 0..56

  for (;;) {
    if (tid == 0) s_item = atomicAdd(counter, 1);
    __syncthreads();                  // broadcast item; fences LDS reuse
    const int item = s_item;
    if (item >= NITEMS) return;       // uniform exit

    // LPT decode: longest q-tiles first
    const int q0 = (31 - item / 24) * 64;
    const int hb = item % 24;
    const int h = hb % 12, b = hb / 12;
    const size_t base = (size_t)(b * Hn + h) * Tn * Dn;   // Q/K [.,T,64]
    const size_t vtb  = (size_t)(b * Hn + h) * Dn * Tn;   // VT  [.,64,T]

    const u16* qp = Q + base + (size_t)(q0 + (wv << 4) + lo) * Dn + (quad << 3);
    const bf16x8 aq0 = *(const bf16x8*)qp;
    const bf16x8 aq1 = *(const bf16x8*)(qp + 32);

    f32x4 o[4] = {f32x4{0,0,0,0}, f32x4{0,0,0,0}, f32x4{0,0,0,0}, f32x4{0,0,0,0}};
    float m1 = MASKVAL;               // running max (UNSCALED score domain)
    float l1 = 0.f;                   // per-lane partial denom (this quad's kv)

    // prologue: stage kv-tile 0 into buffer 0
#pragma unroll
    for (int it = 0; it < 2; it++) {
      const int r = sr + it * 32;
      *(ushort8_t*)&Ksh[r * KP + sc] =
          *(const ushort8_t*)(K + base + (size_t)r * Dn + sc);
      *(ushort8_t*)&Vsh[r * KP + sc] =
          *(const ushort8_t*)(VT + vtb + (size_t)r * Tn + sc);
    }
    __syncthreads();

    int cur = 0;
    const int qrel = (wv << 4) + lo;  // this lane's q-row within the 64-q tile

    for (int j0 = 0; j0 <= q0; j0 += 64) {
      const bool hasnext = (j0 + 64 <= q0);

      // T14: issue next tile's global loads NOW; write to LDS after compute
      ushort8_t kr[2], vr[2];
      if (hasnext) {
#pragma unroll
        for (int it = 0; it < 2; it++) {
          const int r = sr + it * 32;
          kr[it] = *(const ushort8_t*)(K + base + (size_t)(j0 + 64 + r) * Dn + sc);
          vr[it] = *(const ushort8_t*)(VT + vtb + (size_t)r * Tn + j0 + 64 + sc);
        }
      }

      const u16* Kb_ = &Ksh[cur * TILE_W];
      const u16* Vb_ = &Vsh[cur * TILE_W];

      // QK^T swapped: A = K-tile rows (m = kv), B = Q rows (n = q)
      f32x4 s[4];
#pragma unroll
      for (int nt = 0; nt < 4; nt++) {
        const bf16x8 bk0 = *(const bf16x8*)(&Kb_[(nt * 16 + lo) * KP + (quad << 3)]);
        const bf16x8 bk1 = *(const bf16x8*)(&Kb_[(nt * 16 + lo) * KP + 32 + (quad << 3)]);
        f32x4 a = {0.f, 0.f, 0.f, 0.f};
        a = __builtin_amdgcn_mfma_f32_16x16x32_bf16(bk0, aq0, a, 0, 0, 0);
        a = __builtin_amdgcn_mfma_f32_16x16x32_bf16(bk1, aq1, a, 0, 0, 0);
        s[nt] = a;   // s[nt][r] = S[q = qrel][kv = nt*16 + quad*4 + r], UNSCALED
      }

      if (j0 == q0) {
#pragma unroll
        for (int nt = 0; nt < 4; nt++)
#pragma unroll
          for (int r = 0; r < 4; r++) {
            const int kv = nt * 16 + (quad << 2) + r;
            if (kv > qrel) s[nt][r] = MASKVAL;
          }
      }

      // local max over this lane's 16 kv values (no cross-lane in common path)
      const float mxa = fmaxf(fmaxf(s[0][0], s[0][1]), fmaxf(s[0][2], s[0][3]));
      const float mxb = fmaxf(fmaxf(s[1][0], s[1][1]), fmaxf(s[1][2], s[1][3]));
      const float mxc = fmaxf(fmaxf(s[2][0], s[2][1]), fmaxf(s[2][2], s[2][3]));
      const float mxd = fmaxf(fmaxf(s[3][0], s[3][1]), fmaxf(s[3][2], s[3][3]));
      const float pmax = fmaxf(fmaxf(mxa, mxb), fmaxf(mxc, mxd));

      // defer-max: only pay the reduce+rescale when the gap grows too large
      if (!__all(pmax <= m1 + DEFER_THR)) {
        float mx = pmax;
        mx = fmaxf(mx, __shfl_xor(mx, 16));
        mx = fmaxf(mx, __shfl_xor(mx, 32));
        const float mnew = fmaxf(m1, mx);
        const float alpha = safe_exp(0.125f * (m1 - mnew));
        m1 = mnew;
        l1 *= alpha;
        float ar[4];
#pragma unroll
        for (int r = 0; r < 4; r++) ar[r] = __shfl(alpha, (quad << 2) + r);
#pragma unroll
        for (int nt = 0; nt < 4; nt++)
#pragma unroll
          for (int r = 0; r < 4; r++) o[nt][r] *= ar[r];
      }

      // exp with folded 0.125 scale; accumulate per-lane partial denom
      const float mb = 0.125f * m1;
      float sum = 0.f;
#pragma unroll
      for (int nt = 0; nt < 4; nt++)
#pragma unroll
        for (int r = 0; r < 4; r++) {
          const float p = safe_exp(0.125f * s[nt][r] - mb);
          s[nt][r] = p;
          sum += p;
        }
      l1 += sum;

      // P -> LDS bf16: r is kv-contiguous -> one ds_write_b64 per nt
      u16* pw = Pw[wv];
#pragma unroll
      for (int nt = 0; nt < 4; nt++) {
        ushort4 pk;
        pk.x = f2bf(s[nt][0]); pk.y = f2bf(s[nt][1]);
        pk.z = f2bf(s[nt][2]); pk.w = f2bf(s[nt][3]);
        *(ushort4*)&pw[lo * KP + nt * 16 + (quad << 2)] = pk;
      }
      const bf16x8 pa0 = *(const bf16x8*)(&pw[lo * KP + (quad << 3)]);
      const bf16x8 pa1 = *(const bf16x8*)(&pw[lo * KP + 32 + (quad << 3)]);

#pragma unroll
      for (int nt = 0; nt < 4; nt++) {
        const bf16x8 bv0 = *(const bf16x8*)(&Vb_[(nt * 16 + lo) * KP + (quad << 3)]);
        const bf16x8 bv1 = *(const bf16x8*)(&Vb_[(nt * 16 + lo) * KP + 32 + (quad << 3)]);
        o[nt] = __builtin_amdgcn_mfma_f32_16x16x32_bf16(pa0, bv0, o[nt], 0, 0, 0);
        o[nt] = __builtin_amdgcn_mfma_f32_16x16x32_bf16(pa1, bv1, o[nt], 0, 0, 0);
      }

      // write prefetched next tile into the other buffer, then single barrier
      if (hasnext) {
        const int nb = cur ^ 1;
#pragma unroll
        for (int it = 0; it < 2; it++) {
          const int r = sr + it * 32;
          *(ushort8_t*)&Ksh[nb * TILE_W + r * KP + sc] = kr[it];
          *(ushort8_t*)&Vsh[nb * TILE_W + r * KP + sc] = vr[it];
        }
      }
      __syncthreads();
      cur ^= 1;
    }

    // epilogue: reduce per-lane partial l across the 4 quads, then transpose
    float lt = l1;
    lt += __shfl_xor(lt, 16);
    lt += __shfl_xor(lt, 32);
    const float linv = 1.f / lt;
    float ir[4];
#pragma unroll
    for (int r = 0; r < 4; r++) ir[r] = __shfl(linv, (quad << 2) + r);
#pragma unroll
    for (int nt = 0; nt < 4; nt++)
#pragma unroll
      for (int r = 0; r < 4; r++) {
        const int row = q0 + (wv << 4) + (quad << 2) + r;
        const int col = h * 64 + nt * 16 + lo;
        O[(size_t)(b * Tn + row) * Cn + col] = f2bf(o[nt][r] * ir[r]);
      }
  }
}

// ---------------------------------------------------------------------------
extern "C" void kernel_launch(void* const* d_in, const int* in_sizes, int n_in,
                              void* d_out, int out_size, void* d_ws, size_t ws_size,
                              hipStream_t stream) {
  const float* x    = (const float*)d_in[0];   // [B,T,C] fp32
  const float* Wqkv = (const float*)d_in[1];   // [C,3C] fp32
  const float* Wout = (const float*)d_in[2];   // [C,C] fp32
  float* out = (float*)d_out;                  // [B,T,C] fp32

  const size_t per = (size_t)Bn * Hn * Tn * Dn;     // 3,145,728 elems
  u16* xb    = (u16*)d_ws;                          // [4096,768] bf16
  u16* WqkvT = xb + (size_t)Mn * Cn;                // [2304,768] bf16
  u16* WoutT = WqkvT + (size_t)N3n * Cn;            // [768,768]  bf16
  u16* Qb    = WoutT + (size_t)Cn * Cn;             // [B,H,T,DH] bf16
  u16* Kb    = Qb + per;                            // [B,H,T,DH] bf16
  u16* VTb   = Kb + per;                            // [B,H,DH,T] bf16
  u16* attn  = VTb + per;                           // [B,T,C]    bf16
  int* counter = (int*)(attn + (size_t)Mn * Cn);    // 4 B, 4-aligned
  // total ws use: ~36.2 MB + 4 B (< 50.3 MB available)

  cast_bf16<<<(Mn * Cn) / 1024, 256, 0, stream>>>(x, xb, counter);
  transpose_cast<<<dim3(N3n / 32, Cn / 32), dim3(32, 8), 0, stream>>>(Wqkv, WqkvT, Cn, N3n);
  transpose_cast<<<dim3(Cn / 32, Cn / 32), dim3(32, 8), 0, stream>>>(Wout, WoutT, Cn, Cn);

  mfma_gemm<0><<<dim3(N3n / 128, Mn / 128), 256, 0, stream>>>(xb, WqkvT, Qb, Kb, VTb, nullptr);
  attn_kernel<<<dim3(512), 256, 0, stream>>>(Qb, Kb, VTb, attn, counter);
  mfma_gemm<1><<<dim3(Cn / 128, Mn / 128), 256, 0, stream>>>(attn, WoutT, nullptr, nullptr, nullptr, out);
}

// Round 3
// 181.209 us; speedup vs baseline: 1.1688x; 1.0265x over previous
//
#include <hip/hip_runtime.h>
#include <hip/hip_bf16.h>

// Problem constants (B,T,C,H,DH) = (2,2048,768,12,64)
#define Bn 2
#define Tn 2048
#define Cn 768
#define Hn 12
#define Dn 64
#define N3n 2304
#define Mn 4096   // B*T

#define MASKVAL (-30000.f)   // finite sentinel; scores are O(+-40) unscaled
#define NITEMS 768           // 32 q-tiles * 12 heads * 2 batch
#define DEFER_THR 64.f       // unscaled-score gap; P bounded by e^8
#define L2E8 0.1803368801111204f   // 0.125 * log2(e): exp(0.125*x) = exp2(L2E8*x)

typedef unsigned short u16;
typedef __attribute__((ext_vector_type(8))) unsigned short ushort8_t;
typedef __attribute__((ext_vector_type(8))) short bf16x8;   // 8 bf16 in 4 VGPRs
typedef __attribute__((ext_vector_type(4))) float f32x4;
typedef __attribute__((address_space(1))) unsigned int* gas1_t;   // global
typedef __attribute__((address_space(3))) unsigned int* las3_t;   // LDS

__device__ __forceinline__ float bf2f(u16 u) {
  union { unsigned int i; float f; } v; v.i = ((unsigned int)u) << 16; return v.f;
}
__device__ __forceinline__ u16 f2bf(float f) {
  union { float f; unsigned int i; } v; v.f = f;
  return (u16)((v.i + 0x7fffu + ((v.i >> 16) & 1u)) >> 16);
}

// ---------------------------------------------------------------------------
// Prep 1: elementwise fp32 -> bf16 cast (x). Also zeroes the attn work counter.
// ---------------------------------------------------------------------------
__global__ __launch_bounds__(256) void cast_bf16(const float* __restrict__ in,
                                                 u16* __restrict__ out,
                                                 int* __restrict__ counter) {
  if (blockIdx.x == 0 && threadIdx.x == 0) *counter = 0;
  const int i = (blockIdx.x * 256 + threadIdx.x) * 4;
  float4 v = *(const float4*)(in + i);
  ushort4 s;
  s.x = f2bf(v.x); s.y = f2bf(v.y); s.z = f2bf(v.z); s.w = f2bf(v.w);
  *(ushort4*)(out + i) = s;
}

// ---------------------------------------------------------------------------
// Prep 2: transpose-cast. in fp32 [R][Cc] -> out bf16 [Cc][R]. 32x32 LDS tile.
// ---------------------------------------------------------------------------
__global__ __launch_bounds__(256) void transpose_cast(const float* __restrict__ in,
                                                      u16* __restrict__ out,
                                                      int R, int Cc) {
  __shared__ u16 t[32][33];
  const int c0 = blockIdx.x * 32, r0 = blockIdx.y * 32;
  const int tx = threadIdx.x, ty = threadIdx.y;
#pragma unroll
  for (int i = 0; i < 4; i++)
    t[ty * 4 + i][tx] = f2bf(in[(size_t)(r0 + ty * 4 + i) * Cc + c0 + tx]);
  __syncthreads();
#pragma unroll
  for (int i = 0; i < 4; i++)
    out[(size_t)(c0 + ty * 4 + i) * R + r0 + tx] = t[tx][ty * 4 + i];
}

// ---------------------------------------------------------------------------
// MFMA GEMM, m97-structure (R8): 128x128 tile, BK=64, linear LDS [128][64],
// global_load_lds dwordx4 staging (async, no VGPR round-trip), 12 K-steps,
// XCD-chunked block swizzle (nwg % 8 == 0 for both grids: 576 and 192).
// Fragment layout / MFMA / epilogue indexing identical to the verified R5 code.
// ---------------------------------------------------------------------------
#define BK 64

template <int EPI>
__global__ __launch_bounds__(256) void mfma_gemm(const u16* __restrict__ A,
                                                 const u16* __restrict__ BT,
                                                 u16* __restrict__ Q,
                                                 u16* __restrict__ Kd,
                                                 u16* __restrict__ VT,
                                                 float* __restrict__ out) {
  __shared__ __align__(16) u16 Ash[128 * BK];   // 16 KB
  __shared__ __align__(16) u16 Bsh[128 * BK];   // 16 KB
  const int tid = threadIdx.x;
  const int wv = tid >> 6, lane = tid & 63;
  const int lo = lane & 15, quad = lane >> 4;
  const int wm = wv & 1, wn = wv >> 1;

  // XCD-chunked swizzle: physical linear id L lands on XCD L%8 (round-robin);
  // give each XCD a contiguous logical chunk -> per-XCD L2 working set fits.
  const int nwg = gridDim.x * gridDim.y;       // 576 or 192, both % 8 == 0
  const int cpx = nwg >> 3;
  const int lid = blockIdx.y * gridDim.x + blockIdx.x;
  const int swz = (lid & 7) * cpx + (lid >> 3);
  const int n0 = (swz % gridDim.x) * 128;
  const int m0 = (swz / gridDim.x) * 128;

  // staging geometry: one global_load_lds call = 64 lanes x 16 B = 8 rows x 64 B
  const int srow = lane >> 3;          // row within 8-row chunk
  const int scol = (lane & 7) << 3;    // u16 col offset (16-B units)

  f32x4 acc[4][4];
#pragma unroll
  for (int i = 0; i < 4; i++)
#pragma unroll
    for (int j = 0; j < 4; j++) acc[i][j] = f32x4{0.f, 0.f, 0.f, 0.f};

  for (int k0 = 0; k0 < Cn; k0 += BK) {
    __syncthreads();
    // wave wv stages rows [wv*32, wv*32+32) of both tiles, 4 chunks of 8 rows
#pragma unroll
    for (int c = 0; c < 4; c++) {
      const int rb = (wv << 5) + (c << 3);
      const int gr = rb + srow;
      __builtin_amdgcn_global_load_lds(
          (gas1_t)(A + (size_t)(m0 + gr) * Cn + k0 + scol),
          (las3_t)(&Ash[rb * BK]), 16, 0, 0);
      __builtin_amdgcn_global_load_lds(
          (gas1_t)(BT + (size_t)(n0 + gr) * Cn + k0 + scol),
          (las3_t)(&Bsh[rb * BK]), 16, 0, 0);
    }
    __syncthreads();   // compiler drains vmcnt before s_barrier -> LDS valid

    bf16x8 af[4][2], bfr[4][2];
#pragma unroll
    for (int t = 0; t < 4; t++) {
#pragma unroll
      for (int s = 0; s < 2; s++) {
        af[t][s]  = *(const bf16x8*)&Ash[(wm * 64 + t * 16 + lo) * BK + s * 32 + (quad << 3)];
        bfr[t][s] = *(const bf16x8*)&Bsh[(wn * 64 + t * 16 + lo) * BK + s * 32 + (quad << 3)];
      }
    }
#pragma unroll
    for (int mt = 0; mt < 4; mt++)
#pragma unroll
      for (int nt = 0; nt < 4; nt++) {
        acc[mt][nt] = __builtin_amdgcn_mfma_f32_16x16x32_bf16(af[mt][0], bfr[nt][0],
                                                              acc[mt][nt], 0, 0, 0);
        acc[mt][nt] = __builtin_amdgcn_mfma_f32_16x16x32_bf16(af[mt][1], bfr[nt][1],
                                                              acc[mt][nt], 0, 0, 0);
      }
  }

  if (EPI == 0) {
    const int which = n0 / Cn;
    const int h = ((n0 % Cn) >> 6) + wn;
    const int bb = m0 >> 11;
    const int t_base = (m0 & (Tn - 1)) + wm * 64;
    if (which < 2) {
      u16* dst = ((which == 0) ? Q : Kd) + (size_t)(bb * Hn + h) * Tn * Dn;
#pragma unroll
      for (int mt = 0; mt < 4; mt++)
#pragma unroll
        for (int nt = 0; nt < 4; nt++)
#pragma unroll
          for (int r = 0; r < 4; r++) {
            const int t = t_base + mt * 16 + (quad << 2) + r;
            dst[(size_t)t * Dn + nt * 16 + lo] = f2bf(acc[mt][nt][r]);
          }
    } else {
      u16* dst = VT + (size_t)(bb * Hn + h) * Dn * Tn;
#pragma unroll
      for (int mt = 0; mt < 4; mt++)
#pragma unroll
        for (int nt = 0; nt < 4; nt++) {
          const int t = t_base + mt * 16 + (quad << 2);
          const int d = nt * 16 + lo;
          ushort4 st;
          st.x = f2bf(acc[mt][nt][0]); st.y = f2bf(acc[mt][nt][1]);
          st.z = f2bf(acc[mt][nt][2]); st.w = f2bf(acc[mt][nt][3]);
          *(ushort4*)&dst[(size_t)d * Tn + t] = st;
        }
    }
  } else {
#pragma unroll
    for (int mt = 0; mt < 4; mt++)
#pragma unroll
      for (int nt = 0; nt < 4; nt++)
#pragma unroll
        for (int r = 0; r < 4; r++) {
          const int m = m0 + wm * 64 + mt * 16 + (quad << 2) + r;
          out[(size_t)m * Cn + n0 + wn * 64 + nt * 16 + lo] = acc[mt][nt][r];
        }
  }
}

// ---------------------------------------------------------------------------
// Causal flash attention (R8): R7 structure + VALU trims on the common path:
//  * exp via v_exp (exp2 with folded 0.125*log2e); masked scores underflow to
//    0 naturally (arg ~ -5400), so no clamp needed.
//  * P->bf16 pack via v_cvt_pk_bf16_f32 (8 instrs vs ~40 of manual rounding).
//  * max3-shaped local-max chain (8 ops vs 15).
//  * s_setprio(1) around both MFMA clusters (T5; +4-7% on attn per m191).
//  * grid 640 (2.5 blocks/CU avg; LDS 46.6 KB allows 3/CU) — latency-bound
//    loop benefits from co-residency; LPT stealing still balances the tail.
// ---------------------------------------------------------------------------
#define KP 72              // LDS row pitch in u16 (144 B: 16B-aligned)
#define TILE_W (64 * KP)   // one K or V tile in u16

__global__ __launch_bounds__(256) void attn_kernel(const u16* __restrict__ Q,
                                                   const u16* __restrict__ K,
                                                   const u16* __restrict__ VT,
                                                   u16* __restrict__ O,
                                                   int* __restrict__ counter) {
  __shared__ __align__(16) u16 Ksh[2 * TILE_W];   // K tiles  [kv_row][d], x2
  __shared__ __align__(16) u16 Vsh[2 * TILE_W];   // V tiles  [d][kv_row], x2
  __shared__ __align__(16) u16 Pw[4][16 * KP];    // per-wave P [q_row][kv]
  __shared__ int s_item;

  const int tid = threadIdx.x;
  const int wv = tid >> 6, lane = tid & 63;
  const int lo = lane & 15, quad = lane >> 4;
  const int sr = tid >> 3;            // staging row 0..31
  const int sc = (tid & 7) << 3;      // staging col (u16) 0..56

  for (;;) {
    if (tid == 0) s_item = atomicAdd(counter, 1);
    __syncthreads();                  // broadcast item; fences LDS reuse
    const int item = s_item;
    if (item >= NITEMS) return;       // uniform exit

    // LPT decode: longest q-tiles first
    const int q0 = (31 - item / 24) * 64;
    const int hb = item % 24;
    const int h = hb % 12, b = hb / 12;
    const size_t base = (size_t)(b * Hn + h) * Tn * Dn;   // Q/K [.,T,64]
    const size_t vtb  = (size_t)(b * Hn + h) * Dn * Tn;   // VT  [.,64,T]

    const u16* qp = Q + base + (size_t)(q0 + (wv << 4) + lo) * Dn + (quad << 3);
    const bf16x8 aq0 = *(const bf16x8*)qp;
    const bf16x8 aq1 = *(const bf16x8*)(qp + 32);

    f32x4 o[4] = {f32x4{0,0,0,0}, f32x4{0,0,0,0}, f32x4{0,0,0,0}, f32x4{0,0,0,0}};
    float m1 = MASKVAL;               // running max (UNSCALED score domain)
    float l1 = 0.f;                   // per-lane partial denom (this quad's kv)

    // prologue: stage kv-tile 0 into buffer 0
#pragma unroll
    for (int it = 0; it < 2; it++) {
      const int r = sr + it * 32;
      *(ushort8_t*)&Ksh[r * KP + sc] =
          *(const ushort8_t*)(K + base + (size_t)r * Dn + sc);
      *(ushort8_t*)&Vsh[r * KP + sc] =
          *(const ushort8_t*)(VT + vtb + (size_t)r * Tn + sc);
    }
    __syncthreads();

    int cur = 0;
    const int qrel = (wv << 4) + lo;  // this lane's q-row within the 64-q tile

    for (int j0 = 0; j0 <= q0; j0 += 64) {
      const bool hasnext = (j0 + 64 <= q0);

      // T14: issue next tile's global loads NOW; write to LDS after compute
      ushort8_t kr[2], vr[2];
      if (hasnext) {
#pragma unroll
        for (int it = 0; it < 2; it++) {
          const int r = sr + it * 32;
          kr[it] = *(const ushort8_t*)(K + base + (size_t)(j0 + 64 + r) * Dn + sc);
          vr[it] = *(const ushort8_t*)(VT + vtb + (size_t)r * Tn + j0 + 64 + sc);
        }
      }

      const u16* Kb_ = &Ksh[cur * TILE_W];
      const u16* Vb_ = &Vsh[cur * TILE_W];

      // QK^T swapped: A = K-tile rows (m = kv), B = Q rows (n = q)
      f32x4 s[4];
      __builtin_amdgcn_s_setprio(1);
#pragma unroll
      for (int nt = 0; nt < 4; nt++) {
        const bf16x8 bk0 = *(const bf16x8*)(&Kb_[(nt * 16 + lo) * KP + (quad << 3)]);
        const bf16x8 bk1 = *(const bf16x8*)(&Kb_[(nt * 16 + lo) * KP + 32 + (quad << 3)]);
        f32x4 a = {0.f, 0.f, 0.f, 0.f};
        a = __builtin_amdgcn_mfma_f32_16x16x32_bf16(bk0, aq0, a, 0, 0, 0);
        a = __builtin_amdgcn_mfma_f32_16x16x32_bf16(bk1, aq1, a, 0, 0, 0);
        s[nt] = a;   // s[nt][r] = S[q = qrel][kv = nt*16 + quad*4 + r], UNSCALED
      }
      __builtin_amdgcn_s_setprio(0);

      if (j0 == q0) {
#pragma unroll
        for (int nt = 0; nt < 4; nt++)
#pragma unroll
          for (int r = 0; r < 4; r++) {
            const int kv = nt * 16 + (quad << 2) + r;
            if (kv > qrel) s[nt][r] = MASKVAL;
          }
      }

      // local max over this lane's 16 kv values — max3-shaped chain (8 ops)
      float mx = fmaxf(s[0][0], s[0][1]);
      mx = fmaxf(fmaxf(mx, s[0][2]), s[0][3]);
      mx = fmaxf(fmaxf(mx, s[1][0]), s[1][1]);
      mx = fmaxf(fmaxf(mx, s[1][2]), s[1][3]);
      mx = fmaxf(fmaxf(mx, s[2][0]), s[2][1]);
      mx = fmaxf(fmaxf(mx, s[2][2]), s[2][3]);
      mx = fmaxf(fmaxf(mx, s[3][0]), s[3][1]);
      mx = fmaxf(fmaxf(mx, s[3][2]), s[3][3]);
      const float pmax = mx;

      // defer-max: only pay the reduce+rescale when the gap grows too large
      if (!__all(pmax <= m1 + DEFER_THR)) {
        float mr = fmaxf(pmax, __shfl_xor(pmax, 16));
        mr = fmaxf(mr, __shfl_xor(mr, 32));
        const float mnew = fmaxf(m1, mr);
        const float alpha = __builtin_amdgcn_exp2f(L2E8 * (m1 - mnew));
        m1 = mnew;
        l1 *= alpha;
        float ar[4];
#pragma unroll
        for (int r = 0; r < 4; r++) ar[r] = __shfl(alpha, (quad << 2) + r);
#pragma unroll
        for (int nt = 0; nt < 4; nt++)
#pragma unroll
          for (int r = 0; r < 4; r++) o[nt][r] *= ar[r];
      }

      // exp2 with folded 0.125*log2e; masked entries underflow to 0 (no clamp)
      const float mb2 = L2E8 * m1;
      float sum = 0.f;
#pragma unroll
      for (int nt = 0; nt < 4; nt++)
#pragma unroll
        for (int r = 0; r < 4; r++) {
          const float p = __builtin_amdgcn_exp2f(L2E8 * s[nt][r] - mb2);
          s[nt][r] = p;
          sum += p;
        }
      l1 += sum;

      // P -> LDS bf16 via v_cvt_pk_bf16_f32 (RTNE), one 8-B store per nt
      u16* pw = Pw[wv];
#pragma unroll
      for (int nt = 0; nt < 4; nt++) {
        unsigned int p01, p23;
        asm("v_cvt_pk_bf16_f32 %0, %1, %2" : "=v"(p01) : "v"(s[nt][0]), "v"(s[nt][1]));
        asm("v_cvt_pk_bf16_f32 %0, %1, %2" : "=v"(p23) : "v"(s[nt][2]), "v"(s[nt][3]));
        *(uint2*)&pw[lo * KP + nt * 16 + (quad << 2)] = make_uint2(p01, p23);
      }
      const bf16x8 pa0 = *(const bf16x8*)(&pw[lo * KP + (quad << 3)]);
      const bf16x8 pa1 = *(const bf16x8*)(&pw[lo * KP + 32 + (quad << 3)]);

      __builtin_amdgcn_s_setprio(1);
#pragma unroll
      for (int nt = 0; nt < 4; nt++) {
        const bf16x8 bv0 = *(const bf16x8*)(&Vb_[(nt * 16 + lo) * KP + (quad << 3)]);
        const bf16x8 bv1 = *(const bf16x8*)(&Vb_[(nt * 16 + lo) * KP + 32 + (quad << 3)]);
        o[nt] = __builtin_amdgcn_mfma_f32_16x16x32_bf16(pa0, bv0, o[nt], 0, 0, 0);
        o[nt] = __builtin_amdgcn_mfma_f32_16x16x32_bf16(pa1, bv1, o[nt], 0, 0, 0);
      }
      __builtin_amdgcn_s_setprio(0);

      // write prefetched next tile into the other buffer, then single barrier
      if (hasnext) {
        const int nb = cur ^ 1;
#pragma unroll
        for (int it = 0; it < 2; it++) {
          const int r = sr + it * 32;
          *(ushort8_t*)&Ksh[nb * TILE_W + r * KP + sc] = kr[it];
          *(ushort8_t*)&Vsh[nb * TILE_W + r * KP + sc] = vr[it];
        }
      }
      __syncthreads();
      cur ^= 1;
    }

    // epilogue: reduce per-lane partial l across the 4 quads, then transpose
    float lt = l1;
    lt += __shfl_xor(lt, 16);
    lt += __shfl_xor(lt, 32);
    const float linv = 1.f / lt;
    float ir[4];
#pragma unroll
    for (int r = 0; r < 4; r++) ir[r] = __shfl(linv, (quad << 2) + r);
#pragma unroll
    for (int nt = 0; nt < 4; nt++)
#pragma unroll
      for (int r = 0; r < 4; r++) {
        const int row = q0 + (wv << 4) + (quad << 2) + r;
        const int col = h * 64 + nt * 16 + lo;
        O[(size_t)(b * Tn + row) * Cn + col] = f2bf(o[nt][r] * ir[r]);
      }
  }
}

// ---------------------------------------------------------------------------
extern "C" void kernel_launch(void* const* d_in, const int* in_sizes, int n_in,
                              void* d_out, int out_size, void* d_ws, size_t ws_size,
                              hipStream_t stream) {
  const float* x    = (const float*)d_in[0];   // [B,T,C] fp32
  const float* Wqkv = (const float*)d_in[1];   // [C,3C] fp32
  const float* Wout = (const float*)d_in[2];   // [C,C] fp32
  float* out = (float*)d_out;                  // [B,T,C] fp32

  const size_t per = (size_t)Bn * Hn * Tn * Dn;     // 3,145,728 elems
  u16* xb    = (u16*)d_ws;                          // [4096,768] bf16
  u16* WqkvT = xb + (size_t)Mn * Cn;                // [2304,768] bf16
  u16* WoutT = WqkvT + (size_t)N3n * Cn;            // [768,768]  bf16
  u16* Qb    = WoutT + (size_t)Cn * Cn;             // [B,H,T,DH] bf16
  u16* Kb    = Qb + per;                            // [B,H,T,DH] bf16
  u16* VTb   = Kb + per;                            // [B,H,DH,T] bf16
  u16* attn  = VTb + per;                           // [B,T,C]    bf16
  int* counter = (int*)(attn + (size_t)Mn * Cn);    // 4 B, 4-aligned
  // total ws use: ~36.2 MB + 4 B (< 50.3 MB available)

  cast_bf16<<<(Mn * Cn) / 1024, 256, 0, stream>>>(x, xb, counter);
  transpose_cast<<<dim3(N3n / 32, Cn / 32), dim3(32, 8), 0, stream>>>(Wqkv, WqkvT, Cn, N3n);
  transpose_cast<<<dim3(Cn / 32, Cn / 32), dim3(32, 8), 0, stream>>>(Wout, WoutT, Cn, Cn);

  mfma_gemm<0><<<dim3(N3n / 128, Mn / 128), 256, 0, stream>>>(xb, WqkvT, Qb, Kb, VTb, nullptr);
  attn_kernel<<<dim3(640), 256, 0, stream>>>(Qb, Kb, VTb, attn, counter);
  mfma_gemm<1><<<dim3(Cn / 128, Mn / 128), 256, 0, stream>>>(attn, WoutT, nullptr, nullptr, nullptr, out);
}